// Round 1
// baseline (603.610 us; speedup 1.0000x reference)
//
#include <hip/hip_runtime.h>

#define G 32
#define NCELL (G * G * G)       // 32768
#define C_IN 3
#define C_OUT 64

// ws layout (floats):
//   [0,           NCELL*3)          sums    (384 KB)
//   [NCELL*3,     NCELL*4)          cnt     (128 KB)
//   [NCELL*4,     NCELL*4+NCELL*64) convout (8 MB)

__global__ void scatter_kernel(const int* __restrict__ coords,
                               const float* __restrict__ feats,
                               float* __restrict__ sums,
                               float* __restrict__ cnt, int n) {
    int i = blockIdx.x * blockDim.x + threadIdx.x;
    if (i >= n) return;
    int x = coords[i * 3 + 0] >> 4;
    int y = coords[i * 3 + 1] >> 4;
    int z = coords[i * 3 + 2] >> 4;
    int cell = (x * G + y) * G + z;
    atomicAdd(&sums[cell * 3 + 0], feats[i * 3 + 0]);
    atomicAdd(&sums[cell * 3 + 1], feats[i * 3 + 1]);
    atomicAdd(&sums[cell * 3 + 2], feats[i * 3 + 2]);
    atomicAdd(&cnt[cell], 1.0f);
}

__global__ void conv_kernel(const float* __restrict__ sums,
                            const float* __restrict__ cnt,
                            const float* __restrict__ W,     // [64][3][3][3][3]
                            float* __restrict__ convout) {
    __shared__ float wlds[C_OUT * C_IN * 27];   // 5184 floats = 20.25 KB
    for (int t = threadIdx.x; t < C_OUT * C_IN * 27; t += blockDim.x)
        wlds[t] = W[t];
    __syncthreads();

    int cell = blockIdx.x * blockDim.x + threadIdx.x;
    if (cell >= NCELL) return;
    int z = cell & 31;
    int y = (cell >> 5) & 31;
    int x = cell >> 10;

    float acc[C_OUT];
#pragma unroll
    for (int c = 0; c < C_OUT; ++c) acc[c] = 0.f;

    for (int kd = 0; kd < 3; ++kd) {
        int nx = x + kd - 1;
        if (nx < 0 || nx >= G) continue;
        for (int kh = 0; kh < 3; ++kh) {
            int ny = y + kh - 1;
            if (ny < 0 || ny >= G) continue;
            for (int kw = 0; kw < 3; ++kw) {
                int nz = z + kw - 1;
                if (nz < 0 || nz >= G) continue;
                int nc = (nx * G + ny) * G + nz;
                float cv = cnt[nc];
                if (cv <= 0.f) continue;
                float inv = 1.0f / cv;
                float f0 = sums[nc * 3 + 0] * inv;
                float f1 = sums[nc * 3 + 1] * inv;
                float f2 = sums[nc * 3 + 2] * inv;
                int koff = (kd * 3 + kh) * 3 + kw;
#pragma unroll
                for (int co = 0; co < C_OUT; ++co) {
                    const float* wp = &wlds[co * C_IN * 27 + koff];
                    acc[co] += wp[0] * f0 + wp[27] * f1 + wp[54] * f2;
                }
            }
        }
    }
    // occ mask is unnecessary: cells gathered by points always have cnt>=1,
    // and unoccupied cells are never gathered.
    float* op = &convout[cell * C_OUT];
#pragma unroll
    for (int co = 0; co < C_OUT; ++co) op[co] = acc[co];
}

__global__ void gather_kernel(const int* __restrict__ coords,
                              const float4* __restrict__ convout,
                              float4* __restrict__ out, int n) {
    int g = blockIdx.x * blockDim.x + threadIdx.x;
    int i = g >> 4;        // point index
    int c4 = g & 15;       // which float4 of the 64-float row
    if (i >= n) return;
    int x = coords[i * 3 + 0] >> 4;
    int y = coords[i * 3 + 1] >> 4;
    int z = coords[i * 3 + 2] >> 4;
    int cell = (x * G + y) * G + z;
    out[i * 16 + c4] = convout[cell * 16 + c4];
}

extern "C" void kernel_launch(void* const* d_in, const int* in_sizes, int n_in,
                              void* d_out, int out_size, void* d_ws, size_t ws_size,
                              hipStream_t stream) {
    const int*   coords = (const int*)d_in[0];
    const float* feats  = (const float*)d_in[1];
    const float* W      = (const float*)d_in[2];
    float* out     = (float*)d_out;
    float* sums    = (float*)d_ws;
    float* cnt     = sums + NCELL * 3;
    float* convout = cnt + NCELL;

    int n = in_sizes[0] / 3;   // 2,000,000

    // zero the accumulator region (sums + cnt) each call
    hipMemsetAsync(d_ws, 0, NCELL * 4 * sizeof(float), stream);

    scatter_kernel<<<(n + 255) / 256, 256, 0, stream>>>(coords, feats, sums, cnt, n);
    conv_kernel<<<(NCELL + 255) / 256, 256, 0, stream>>>(sums, cnt, W, convout);

    long total = (long)n * 16;
    gather_kernel<<<(int)((total + 255) / 256), 256, 0, stream>>>(
        coords, (const float4*)convout, (float4*)out, n);
}

// Round 2
// 262.996 us; speedup vs baseline: 2.2951x; 2.2951x over previous
//
#include <hip/hip_runtime.h>

#define G 32
#define NCELL (G * G * G)       // 32768
#define C_IN 3
#define C_OUT 64

// ---------------- histogram scatter (no global atomics) ----------------
// Block b: vtype = b&3 (0..2 = feat channel, 3 = count), chunk = b>>2.
// Each block accumulates ONE value for ALL 32768 cells in a 128 KB LDS
// histogram over its point chunk, then writes the partial non-atomically.
__global__ __launch_bounds__(1024) void histo_kernel(
    const int* __restrict__ coords,
    const float* __restrict__ feats,
    float* __restrict__ partial,   // [4][P][NCELL]
    int* __restrict__ cellid,      // [n]
    int n, int P, int ppc) {
    __shared__ float h[NCELL];     // 128 KB static (gfx950 LDS = 160 KB)
    int vtype = blockIdx.x & 3;
    int chunk = blockIdx.x >> 2;

    float4* h4 = (float4*)h;
    for (int t = threadIdx.x; t < NCELL / 4; t += blockDim.x)
        h4[t] = make_float4(0.f, 0.f, 0.f, 0.f);
    __syncthreads();

    int start = chunk * ppc;
    int end = start + ppc; if (end > n) end = n;
    for (int i = start + threadIdx.x; i < end; i += blockDim.x) {
        int x = coords[i * 3 + 0] >> 4;
        int y = coords[i * 3 + 1] >> 4;
        int z = coords[i * 3 + 2] >> 4;
        int cell = (x * G + y) * G + z;
        float v;
        if (vtype < 3) {
            v = feats[i * 3 + vtype];
        } else {
            v = 1.0f;
            cellid[i] = cell;      // persist for gather
        }
        atomicAdd(&h[cell], v);    // LDS atomic — cheap, pipelined
    }
    __syncthreads();

    float4* pp = (float4*)(partial + (size_t)(vtype * P + chunk) * NCELL);
    for (int t = threadIdx.x; t < NCELL / 4; t += blockDim.x)
        pp[t] = h4[t];
}

__global__ void reduce_kernel(const float* __restrict__ partial,
                              float* __restrict__ sums,
                              float* __restrict__ cnt, int P) {
    int t = blockIdx.x * blockDim.x + threadIdx.x;   // 4*NCELL threads
    int v = t >> 15;
    int cell = t & (NCELL - 1);
    const float* base = partial + ((size_t)v * P) * NCELL + cell;
    float acc = 0.f;
    for (int p = 0; p < P; ++p) acc += base[(size_t)p * NCELL];
    if (v < 3) sums[cell * 3 + v] = acc;
    else       cnt[cell] = acc;
}

// ---------------- fallback atomic scatter (only if ws too small) -------
__global__ void scatter_atomic_kernel(const int* __restrict__ coords,
                                      const float* __restrict__ feats,
                                      float* __restrict__ sums,
                                      float* __restrict__ cnt, int n) {
    int i = blockIdx.x * blockDim.x + threadIdx.x;
    if (i >= n) return;
    int x = coords[i * 3 + 0] >> 4;
    int y = coords[i * 3 + 1] >> 4;
    int z = coords[i * 3 + 2] >> 4;
    int cell = (x * G + y) * G + z;
    atomicAdd(&sums[cell * 3 + 0], feats[i * 3 + 0]);
    atomicAdd(&sums[cell * 3 + 1], feats[i * 3 + 1]);
    atomicAdd(&sums[cell * 3 + 2], feats[i * 3 + 2]);
    atomicAdd(&cnt[cell], 1.0f);
}

// ---------------- dense 3^3 conv on the 32^3 coarse grid ---------------
__global__ void conv_kernel(const float* __restrict__ sums,
                            const float* __restrict__ cnt,
                            const float* __restrict__ W,     // [64][3][27]
                            float* __restrict__ convout) {
    __shared__ float wlds[C_OUT * C_IN * 27];
    for (int t = threadIdx.x; t < C_OUT * C_IN * 27; t += blockDim.x)
        wlds[t] = W[t];
    __syncthreads();

    int cell = blockIdx.x * blockDim.x + threadIdx.x;
    if (cell >= NCELL) return;
    int z = cell & 31;
    int y = (cell >> 5) & 31;
    int x = cell >> 10;

    float acc[C_OUT];
#pragma unroll
    for (int c = 0; c < C_OUT; ++c) acc[c] = 0.f;

    for (int kd = 0; kd < 3; ++kd) {
        int nx = x + kd - 1;
        if (nx < 0 || nx >= G) continue;
        for (int kh = 0; kh < 3; ++kh) {
            int ny = y + kh - 1;
            if (ny < 0 || ny >= G) continue;
            for (int kw = 0; kw < 3; ++kw) {
                int nz = z + kw - 1;
                if (nz < 0 || nz >= G) continue;
                int nc = (nx * G + ny) * G + nz;
                float cv = cnt[nc];
                if (cv <= 0.f) continue;
                float inv = 1.0f / cv;
                float f0 = sums[nc * 3 + 0] * inv;
                float f1 = sums[nc * 3 + 1] * inv;
                float f2 = sums[nc * 3 + 2] * inv;
                int koff = (kd * 3 + kh) * 3 + kw;
#pragma unroll
                for (int co = 0; co < C_OUT; ++co) {
                    const float* wp = &wlds[co * C_IN * 27 + koff];
                    acc[co] += wp[0] * f0 + wp[27] * f1 + wp[54] * f2;
                }
            }
        }
    }
    float* op = &convout[(size_t)cell * C_OUT];
#pragma unroll
    for (int co = 0; co < C_OUT; ++co) op[co] = acc[co];
}

// ---------------- gather: broadcast cell rows to points ----------------
__global__ void gather_kernel(const int* __restrict__ cellid,
                              const float4* __restrict__ convout,
                              float4* __restrict__ out, int n) {
    long g = (long)blockIdx.x * blockDim.x + threadIdx.x;
    int i = (int)(g >> 4);
    int c4 = (int)(g & 15);
    if (i >= n) return;
    int cell = cellid[i];
    out[(size_t)i * 16 + c4] = convout[(size_t)cell * 16 + c4];
}

__global__ void gather_coords_kernel(const int* __restrict__ coords,
                                     const float4* __restrict__ convout,
                                     float4* __restrict__ out, int n) {
    long g = (long)blockIdx.x * blockDim.x + threadIdx.x;
    int i = (int)(g >> 4);
    int c4 = (int)(g & 15);
    if (i >= n) return;
    int x = coords[i * 3 + 0] >> 4;
    int y = coords[i * 3 + 1] >> 4;
    int z = coords[i * 3 + 2] >> 4;
    int cell = (x * G + y) * G + z;
    out[(size_t)i * 16 + c4] = convout[(size_t)cell * 16 + c4];
}

extern "C" void kernel_launch(void* const* d_in, const int* in_sizes, int n_in,
                              void* d_out, int out_size, void* d_ws, size_t ws_size,
                              hipStream_t stream) {
    const int*   coords = (const int*)d_in[0];
    const float* feats  = (const float*)d_in[1];
    const float* W      = (const float*)d_in[2];
    float* out = (float*)d_out;
    int n = in_sizes[0] / 3;   // 2,000,000

    // ws layout (floats): sums[NCELL*3] | cnt[NCELL] | convout[NCELL*64]
    //                     | cellid[n] (int) | partial[4*P*NCELL]
    float* sums    = (float*)d_ws;
    float* cnt     = sums + NCELL * 3;
    float* convout = cnt + NCELL;
    int*   cellid  = (int*)(convout + (size_t)NCELL * 64);
    float* partial = (float*)(cellid + n);

    size_t fixed_bytes = ((size_t)NCELL * 3 + NCELL + (size_t)NCELL * 64 + n) * 4;
    long avail = (long)ws_size - (long)fixed_bytes;
    int P = avail > 0 ? (int)(avail / ((size_t)4 * NCELL * 4)) : 0;
    if (P > 64) P = 64;

    long total = (long)n * 16;
    if (P >= 1) {
        int ppc = (n + P - 1) / P;
        histo_kernel<<<4 * P, 1024, 0, stream>>>(coords, feats, partial, cellid, n, P, ppc);
        reduce_kernel<<<(4 * NCELL) / 256, 256, 0, stream>>>(partial, sums, cnt, P);
        conv_kernel<<<(NCELL + 255) / 256, 256, 0, stream>>>(sums, cnt, W, convout);
        gather_kernel<<<(int)((total + 255) / 256), 256, 0, stream>>>(
            cellid, (const float4*)convout, (float4*)out, n);
    } else {
        // ws too small for partials: fall back to atomic scatter
        hipMemsetAsync(d_ws, 0, NCELL * 4 * sizeof(float), stream);
        scatter_atomic_kernel<<<(n + 255) / 256, 256, 0, stream>>>(coords, feats, sums, cnt, n);
        conv_kernel<<<(NCELL + 255) / 256, 256, 0, stream>>>(sums, cnt, W, convout);
        gather_coords_kernel<<<(int)((total + 255) / 256), 256, 0, stream>>>(
            coords, (const float4*)convout, (float4*)out, n);
    }
}